// Round 5
// baseline (249.137 us; speedup 1.0000x reference)
//
#include <hip/hip_runtime.h>
#include <hip/hip_bf16.h>

#define M_DIM 4096
#define N_DIM 4096
#define K_DIM 4096

typedef __attribute__((ext_vector_type(4))) int i32x4;
typedef __attribute__((ext_vector_type(16))) int i32x16;

typedef __attribute__((address_space(1))) const void GV;
typedef __attribute__((address_space(3))) void LV;

// ---------------------------------------------------------------------------
// Fused pre-kernel.
//  blocks [0,1024):    hadamard (FWHT over 64 groups) + per-token absmax
//                      int8 quant; writes xq (i8) + sx (f32/token).
//  blocks [1024,2048): weight int8 recovery: per-row scale = absmax/127
//                      (exact inverse of setup-time per-channel QDQ);
//                      writes wq (i8) + sw (f32/row).
// ---------------------------------------------------------------------------
__global__ __launch_bounds__(256) void prequant_kernel(const float* __restrict__ x,
                                                       const float* __restrict__ w,
                                                       char* __restrict__ xq,
                                                       char* __restrict__ wq,
                                                       float* __restrict__ sx,
                                                       float* __restrict__ sw) {
  const int wave = threadIdx.x >> 6;
  const int lane = threadIdx.x & 63;

  if (blockIdx.x >= 1024) {
    // ---- weight row: recover integer codes exactly
    const int row = (blockIdx.x - 1024) * 4 + wave;
    const float* wp = w + (size_t)row * 4096;
    float4 v[16];
#pragma unroll
    for (int c = 0; c < 16; ++c) v[c] = *(const float4*)(wp + c * 256 + lane * 4);
    float amax = 0.f;
#pragma unroll
    for (int c = 0; c < 16; ++c)
      amax = fmaxf(amax, fmaxf(fmaxf(fabsf(v[c].x), fabsf(v[c].y)),
                               fmaxf(fabsf(v[c].z), fabsf(v[c].w))));
#pragma unroll
    for (int off = 32; off >= 1; off >>= 1) amax = fmaxf(amax, __shfl_xor(amax, off, 64));
    amax = fmaxf(amax, 1e-30f);
    const float inv = 127.0f / amax;  // w = iw*s with amax = 127*s  ->  w*inv = iw
    char* op = wq + (size_t)row * 4096;
#pragma unroll
    for (int c = 0; c < 16; ++c) {
      char4 o;
      o.x = (char)rintf(v[c].x * inv);
      o.y = (char)rintf(v[c].y * inv);
      o.z = (char)rintf(v[c].z * inv);
      o.w = (char)rintf(v[c].w * inv);
      *(char4*)(op + c * 256 + lane * 4) = o;
    }
    if (lane == 0) sw[row] = amax * (1.0f / 127.0f);
    return;
  }

  // ---- hadamard + per-token int8 quant
  const int tok = blockIdx.x * 4 + wave;
  const int gs = lane >> 4;  // quarter of g-space
  const int q = lane & 15;   // d-quad: d = q*4..q*4+3
  const float* xp = x + (size_t)tok * 4096;

  float4 v[16];  // lane holds g = gl*4+gs, gl=0..15, float4 over d
#pragma unroll
  for (int gl = 0; gl < 16; ++gl)
    v[gl] = *(const float4*)(xp + (gl * 4 + gs) * 64 + q * 4);

  // in-lane FWHT stages (g-bits 4,8,16,32 <=> gl-bits 1,2,4,8)
#pragma unroll
  for (int s = 1; s < 16; s <<= 1) {
#pragma unroll
    for (int i = 0; i < 16; ++i) {
      if ((i & s) == 0) {
        float4 a = v[i], b = v[i | s];
        v[i].x = a.x + b.x; v[i].y = a.y + b.y; v[i].z = a.z + b.z; v[i].w = a.w + b.w;
        v[i | s].x = a.x - b.x; v[i | s].y = a.y - b.y;
        v[i | s].z = a.z - b.z; v[i | s].w = a.w - b.w;
      }
    }
  }
  // cross-lane stages: g-bit 1 <=> lane^16, g-bit 2 <=> lane^32
#pragma unroll
  for (int st = 0; st < 2; ++st) {
    const int L = 16 << st;
    const bool hi = (lane & L) != 0;
#pragma unroll
    for (int i = 0; i < 16; ++i) {
      float4 t;
      t.x = __shfl_xor(v[i].x, L, 64);
      t.y = __shfl_xor(v[i].y, L, 64);
      t.z = __shfl_xor(v[i].z, L, 64);
      t.w = __shfl_xor(v[i].w, L, 64);
      if (hi) {
        v[i].x = t.x - v[i].x; v[i].y = t.y - v[i].y;
        v[i].z = t.z - v[i].z; v[i].w = t.w - v[i].w;
      } else {
        v[i].x += t.x; v[i].y += t.y; v[i].z += t.z; v[i].w += t.w;
      }
    }
  }

  float amax = 0.f;
#pragma unroll
  for (int i = 0; i < 16; ++i) {
    v[i].x *= 0.125f; v[i].y *= 0.125f; v[i].z *= 0.125f; v[i].w *= 0.125f;  // 1/sqrt(64)
    amax = fmaxf(amax, fmaxf(fmaxf(fabsf(v[i].x), fabsf(v[i].y)),
                             fmaxf(fabsf(v[i].z), fabsf(v[i].w))));
  }
#pragma unroll
  for (int off = 32; off >= 1; off >>= 1) amax = fmaxf(amax, __shfl_xor(amax, off, 64));

  const float s = fmaxf(amax * (1.0f / 127.0f), 1e-5f);  // reference clip
  const float inv = 1.0f / s;

  char* op = xq + (size_t)tok * 4096;
#pragma unroll
  for (int gl = 0; gl < 16; ++gl) {
    char4 o;
    o.x = (char)rintf(v[gl].x * inv);
    o.y = (char)rintf(v[gl].y * inv);
    o.z = (char)rintf(v[gl].z * inv);
    o.w = (char)rintf(v[gl].w * inv);
    *(char4*)(op + (gl * 4 + gs) * 64 + q * 4) = o;
  }
  if (lane == 0) sx[tok] = s;
}

// ---------------------------------------------------------------------------
// Exact int8 GEMM: C[m][n] = sx[m]*sw[n] * (sum_k ix[m][k]*iw[n][k]) + bias[n]
// 128x128 tile, BK=128, DOUBLE-BUFFERED LDS (2x32KB = 64KB): single barrier
// per K-tile; tile t+1's global_load_lds issue right after the barrier and
// fly during compute of tile t, so the compiler's vmcnt(0)-before-s_barrier
// drains loads that already had a full compute phase in flight.
// XOR-8 swizzle: 16B segment `seg` of row r lives in slot seg^(r&7).
// ---------------------------------------------------------------------------
__global__ __launch_bounds__(256, 2) void gemm_i8(const char* __restrict__ A,
                                                  const char* __restrict__ B,
                                                  const float* __restrict__ sx,
                                                  const float* __restrict__ sw,
                                                  const float* __restrict__ bias,
                                                  float* __restrict__ C) {
  __shared__ char As[2][128 * 128];
  __shared__ char Bs[2][128 * 128];

  const int tid = threadIdx.x;
  const int lane = tid & 63;
  const int wave = tid >> 6;
  const int bm = blockIdx.y, bn = blockIdx.x;
  const int wm = wave >> 1, wn = wave & 1;

  // ---- staging: thread tid stages 4x16B per matrix per tile; chunk c ->
  //      LDS offset c*4096 + tid*16 == row (c*32 + tid>>3), slot tid&7.
  //      fetch global seg = (tid&7) ^ ((tid>>3)&7)
  const int trow = tid >> 3;  // 0..31
  const int tseg = (tid & 7) ^ (trow & 7);
  const char* gA = A + (size_t)(bm * 128 + trow) * K_DIM + tseg * 16;
  const char* gB = B + (size_t)(bn * 128 + trow) * K_DIM + tseg * 16;
  const int ldst = tid * 16;

  // ---- fragment addressing: row = w?*64 + i*32 + m32 (byte stride 128);
  //      logical seg = kc*2 + half, slot = seg ^ (row&7) = seg ^ (m32&7)
  const int m32 = lane & 31;
  const int half = lane >> 5;
  const int aBase = (wm * 64 + m32) * 128;
  const int bBase = (wn * 64 + m32) * 128;
  int sl[4];
#pragma unroll
  for (int kc = 0; kc < 4; ++kc) sl[kc] = ((kc * 2 + half) ^ (m32 & 7)) * 16;

  i32x16 acc[2][2];
#pragma unroll
  for (int i = 0; i < 2; ++i)
#pragma unroll
    for (int j = 0; j < 2; ++j)
#pragma unroll
      for (int r = 0; r < 16; ++r) acc[i][j][r] = 0;

  auto stage = [&](int kt, int b) {
    const size_t ke = (size_t)kt * 128;
#pragma unroll
    for (int c = 0; c < 4; ++c) {
      __builtin_amdgcn_global_load_lds((GV*)(gA + ke + (size_t)c * 32 * K_DIM),
                                       (LV*)(&As[b][ldst + c * 4096]), 16, 0, 0);
      __builtin_amdgcn_global_load_lds((GV*)(gB + ke + (size_t)c * 32 * K_DIM),
                                       (LV*)(&Bs[b][ldst + c * 4096]), 16, 0, 0);
    }
  };

  auto compute = [&](int b) {
#pragma unroll
    for (int kc = 0; kc < 4; ++kc) {
      i32x4 a0 = *(const i32x4*)&As[b][aBase + sl[kc]];
      i32x4 a1 = *(const i32x4*)&As[b][aBase + 4096 + sl[kc]];
      i32x4 b0 = *(const i32x4*)&Bs[b][bBase + sl[kc]];
      i32x4 b1 = *(const i32x4*)&Bs[b][bBase + 4096 + sl[kc]];
      acc[0][0] = __builtin_amdgcn_mfma_i32_32x32x32_i8(a0, b0, acc[0][0], 0, 0, 0);
      acc[0][1] = __builtin_amdgcn_mfma_i32_32x32x32_i8(a0, b1, acc[0][1], 0, 0, 0);
      acc[1][0] = __builtin_amdgcn_mfma_i32_32x32x32_i8(a1, b0, acc[1][0], 0, 0, 0);
      acc[1][1] = __builtin_amdgcn_mfma_i32_32x32x32_i8(a1, b1, acc[1][1], 0, 0, 0);
    }
  };

  stage(0, 0);
  const int NT = K_DIM / 128;  // 32, even
  for (int kt = 0; kt < NT; kt += 2) {
    __syncthreads();                       // buf0 staged & buf1 consumers done
    if (kt + 1 < NT) stage(kt + 1, 1);     // flies during compute(0)
    compute(0);
    __syncthreads();                       // buf1 staged & buf0 consumers done
    if (kt + 2 < NT) stage(kt + 2, 0);     // flies during compute(1)
    compute(1);
  }

  // ---- epilogue: C/D layout col=lane&31, row=(r&3)+8*(r>>2)+4*(lane>>5)
  float swv[2], bv[2];
#pragma unroll
  for (int j = 0; j < 2; ++j) {
    const int colg = bn * 128 + wn * 64 + j * 32 + m32;
    swv[j] = sw[colg];
    bv[j] = bias[colg];
  }

#pragma unroll
  for (int i = 0; i < 2; ++i) {
    const int rbase = bm * 128 + wm * 64 + i * 32 + 4 * half;
    float sxv[16];
#pragma unroll
    for (int r = 0; r < 16; ++r) sxv[r] = sx[rbase + (r & 3) + 8 * (r >> 2)];
#pragma unroll
    for (int j = 0; j < 2; ++j) {
      const int colg = bn * 128 + wn * 64 + j * 32 + m32;
#pragma unroll
      for (int r = 0; r < 16; ++r) {
        const int rowg = rbase + (r & 3) + 8 * (r >> 2);
        C[(size_t)rowg * N_DIM + colg] = (float)acc[i][j][r] * (sxv[r] * swv[j]) + bv[j];
      }
    }
  }
}

// ---------------------------------------------------------------------------
extern "C" void kernel_launch(void* const* d_in, const int* in_sizes, int n_in,
                              void* d_out, int out_size, void* d_ws, size_t ws_size,
                              hipStream_t stream) {
  const float* x = (const float*)d_in[0];     // (2,2048,4096) fp32
  const float* w = (const float*)d_in[1];     // (4096,4096) fp32 (pre-quantized)
  const float* bias = (const float*)d_in[2];  // (4096,) fp32

  char* xq = (char*)d_ws;                                   // 16 MB i8
  char* wq = xq + (size_t)M_DIM * K_DIM;                    // 16 MB i8
  float* sx = (float*)(wq + (size_t)N_DIM * K_DIM);         // 16 KB
  float* sw = sx + M_DIM;                                   // 16 KB
  float* out = (float*)d_out;

  prequant_kernel<<<2048, 256, 0, stream>>>(x, w, xq, wq, sx, sw);

  dim3 grid(N_DIM / 128, M_DIM / 128);
  gemm_i8<<<grid, 256, 0, stream>>>(xq, wq, sx, sw, bias, out);
}